// Round 5
// baseline (189.259 us; speedup 1.0000x reference)
//
#include <hip/hip_runtime.h>

// Problem constants (B=2, L=16, D=4, K=2, N_IN=8, N_OUT=8, NC=3)
#define NSITES (2 * 16 * 16 * 16 * 16)          // 131072 sites
// W:     site-stride 72  floats (8 ch * 3*3), base 288 B (16B aligned)
// U_PT:  site-stride 180 floats (4 mu * 5 ik * 3*3)
// omega: flat [i][j][mu][ik] = i*160 + j*20 + mu*5 + ik  (1280 floats)
// out:   site-stride 72 floats
//
// Decomposition: 4 threads/site (one per mu). Each thread: all 8 output
// channels, elementwise sandwich (no M/V temps -> lowest VGPR pressure),
// mu-partials reduced via shfl_xor(1,2), store spread over all 4 lanes.

// LDS omega: [mu][ik][j][i], mu-stride 328 floats (1312 B).
// Per (ik,j) read: 4 distinct addresses (one per mu), banks
// (mu*328)%32 = {0,8,16,24} -> each b128 spans disjoint bank quads,
// 16-lane same-address broadcast -> conflict-free.
#define OM_MU_STRIDE 328

__global__ __launch_bounds__(256) void lconv_kernel(
    const float* __restrict__ W, const float* __restrict__ U_PT,
    const float* __restrict__ omega, float* __restrict__ out)
{
    __shared__ float s_om[4 * OM_MU_STRIDE];
    for (int t = threadIdx.x; t < 1280; t += 256) {
        const int i  = t / 160;
        const int r  = t - i * 160;
        const int j  = r / 20;
        const int r2 = r - j * 20;
        const int m  = r2 / 5;
        const int ik = r2 - m * 5;
        s_om[m * OM_MU_STRIDE + ik * 64 + j * 8 + i] = omega[t];
    }
    __syncthreads();

    // XCD-aware bijective swizzle: 2048 blocks, 8 XCDs, 256-block chunks.
    const int bid = ((int)blockIdx.x & 7) * ((int)gridDim.x >> 3)
                  + ((int)blockIdx.x >> 3);
    const int idx = bid * 256 + (int)threadIdx.x;
    const int s   = idx >> 2;         // site (64 consecutive sites per block)
    const int mu  = idx & 3;          // this thread's axis
    const int sh  = 12 - 4 * mu;      // bit position of x_mu in s
    const int x   = (s >> sh) & 15;

    const float* __restrict__ Ub  = U_PT + (size_t)s * 180 + mu * 45;
    const float* __restrict__ omt = s_om + mu * OM_MU_STRIDE;

    float acc[8][9];
#pragma unroll
    for (int i = 0; i < 8; ++i)
#pragma unroll
        for (int e = 0; e < 9; ++e) acc[i][e] = 0.0f;

#pragma unroll 1
    for (int ik = 0; ik < 5; ++ik) {
        const int k = ik - 2;
        float U[9];
#pragma unroll
        for (int e = 0; e < 9; ++e) U[e] = Ub[ik * 9 + e];

        // neighbor site along mu
        const int ns = s + ((((x + k + 16) & 15) - x) << sh);
        const float4* __restrict__ Wn4 =
            reinterpret_cast<const float4*>(W + (size_t)ns * 72);

#pragma unroll
        for (int j = 0; j < 8; ++j) {
            // channel j = floats j*9 .. j*9+8; covered by 3 float4s
            const int f4b = (j * 9) >> 2;
            const int off = (j * 9) & 3;
            float Wf[12];
#pragma unroll
            for (int q = 0; q < 3; ++q) {
                const float4 v = Wn4[f4b + q];
                Wf[q * 4 + 0] = v.x; Wf[q * 4 + 1] = v.y;
                Wf[q * 4 + 2] = v.z; Wf[q * 4 + 3] = v.w;
            }
            // omega[i=0..7, j, mu, ik] as two b128 (conflict-free, broadcast)
            const float4 w0 = *reinterpret_cast<const float4*>(
                                  omt + ik * 64 + j * 8);
            const float4 w1 = *reinterpret_cast<const float4*>(
                                  omt + ik * 64 + j * 8 + 4);
            const float w[8] = {w0.x, w0.y, w0.z, w0.w,
                                w1.x, w1.y, w1.z, w1.w};
            // elementwise sandwich: row a of U*W_j, then element (a,b)
#pragma unroll
            for (int a = 0; a < 3; ++a) {
                const float uw0 = fmaf(U[a * 3 + 0], Wf[off + 0],
                                  fmaf(U[a * 3 + 1], Wf[off + 3],
                                       U[a * 3 + 2] * Wf[off + 6]));
                const float uw1 = fmaf(U[a * 3 + 0], Wf[off + 1],
                                  fmaf(U[a * 3 + 1], Wf[off + 4],
                                       U[a * 3 + 2] * Wf[off + 7]));
                const float uw2 = fmaf(U[a * 3 + 0], Wf[off + 2],
                                  fmaf(U[a * 3 + 1], Wf[off + 5],
                                       U[a * 3 + 2] * Wf[off + 8]));
#pragma unroll
                for (int b2 = 0; b2 < 3; ++b2) {
                    const float m = fmaf(uw0, U[b2 * 3 + 0],
                                    fmaf(uw1, U[b2 * 3 + 1],
                                         uw2 * U[b2 * 3 + 2]));
#pragma unroll
                    for (int i = 0; i < 8; ++i)
                        acc[i][a * 3 + b2] =
                            fmaf(w[i], m, acc[i][a * 3 + b2]);
                }
            }
        }
    }

    // reduce the 4 mu-partials within each lane group of 4
#pragma unroll
    for (int i = 0; i < 8; ++i)
#pragma unroll
        for (int e = 0; e < 9; ++e) {
            float v = acc[i][e];
            v += __shfl_xor(v, 1);
            v += __shfl_xor(v, 2);
            acc[i][e] = v;
        }

    // all 4 lanes of the group store: lane mu writes float4 chunks
    // q = mu, mu+4, mu+8, mu+12 (+16 for mu<2) of the 18-float4 site block
    {
        float4* __restrict__ o4 = reinterpret_cast<float4*>(out + (size_t)s * 72);
#pragma unroll
        for (int t = 0; t < 4; ++t) {
            const int q = t * 4 + mu;
            const int f = q * 4;
            o4[q] = make_float4(acc[(f + 0) / 9][(f + 0) % 9],
                                acc[(f + 1) / 9][(f + 1) % 9],
                                acc[(f + 2) / 9][(f + 2) % 9],
                                acc[(f + 3) / 9][(f + 3) % 9]);
        }
        if (mu < 2) {
            const int q = 16 + mu;
            const int f = q * 4;
            o4[q] = make_float4(acc[(f + 0) / 9][(f + 0) % 9],
                                acc[(f + 1) / 9][(f + 1) % 9],
                                acc[(f + 2) / 9][(f + 2) % 9],
                                acc[(f + 3) / 9][(f + 3) % 9]);
        }
    }
}

extern "C" void kernel_launch(void* const* d_in, const int* in_sizes, int n_in,
                              void* d_out, int out_size, void* d_ws, size_t ws_size,
                              hipStream_t stream) {
    const float* W   = (const float*)d_in[0];
    const float* U   = (const float*)d_in[1];
    const float* om  = (const float*)d_in[2];
    float*       out = (float*)d_out;

    const int block = 256;
    const int grid  = (NSITES * 4) / block;   // 2048 blocks
    hipLaunchKernelGGL(lconv_kernel, dim3(grid), dim3(block), 0, stream,
                       W, U, om, out);
}

// Round 6
// 121.645 us; speedup vs baseline: 1.5558x; 1.5558x over previous
//
#include <hip/hip_runtime.h>

// Problem constants (B=2, L=16, D=4, K=2, N_IN=8, N_OUT=8, NC=3)
#define NSITES (2 * 16 * 16 * 16 * 16)          // 131072 sites
// W:     site-stride 72  floats (8 ch * 3*3), base 288 B (16B aligned)
// U_PT:  site-stride 180 floats (4 mu * 5 ik * 3*3)
// omega: flat [i][j][mu][ik] = i*160 + j*20 + mu*5 + ik  (1280 floats)
// out:   site-stride 72 floats
//
// Decomposition: 8 threads/site = (jh, mu).
//   lane bits: [..site..][jh][mu1 mu0]
//   Each thread: loads its own 4 W channels (j = jh*4+t), computes sandwich
//   M_j = U W_j U^T for those, exchanges M with the partner (lane^4) via
//   shfl_xor, and mixes into its own 4 OUTPUT channels (i = jh*4+i').
//   mu-partials reduced via shfl_xor(1,2); mu==0 lanes store (compile-time
//   indices only -- R5's runtime-indexed store caused scratch spill).

#define OM_MU_STRIDE 328   // [mu][ik][j][i], mu-pad: 5*8*8=320 -> 328

__global__ __launch_bounds__(256) void lconv_kernel(
    const float* __restrict__ W, const float* __restrict__ U_PT,
    const float* __restrict__ omega, float* __restrict__ out)
{
    __shared__ float s_om[4 * OM_MU_STRIDE];
    for (int t = threadIdx.x; t < 1280; t += 256) {
        const int i  = t / 160;
        const int r  = t - i * 160;
        const int j  = r / 20;
        const int r2 = r - j * 20;
        const int m  = r2 / 5;
        const int ik = r2 - m * 5;
        s_om[m * OM_MU_STRIDE + ik * 64 + j * 8 + i] = omega[t];
    }
    __syncthreads();

    // XCD-aware bijective swizzle: 4096 blocks, 8 XCDs, 512-block chunks.
    const int bid = ((int)blockIdx.x & 7) * ((int)gridDim.x >> 3)
                  + ((int)blockIdx.x >> 3);
    const int idx = bid * 256 + (int)threadIdx.x;
    const int s   = idx >> 3;         // site (32 consecutive sites per block)
    const int jh  = (idx >> 2) & 1;   // j-half AND i-half of this thread
    const int mu  = idx & 3;          // axis
    const int sh  = 12 - 4 * mu;      // bit position of x_mu in s
    const int x   = (s >> sh) & 15;

    const float* __restrict__ Ub  = U_PT + (size_t)s * 180 + mu * 45;
    // omega base for this (mu, i-half): + ik*64 + j*8 per read
    const float* __restrict__ omt = s_om + mu * OM_MU_STRIDE + jh * 4;
    const int jown8 = jh * 32;          // (jh*4)*8
    const int jpar8 = (jh ^ 1) * 32;

    float acc[4][9];
#pragma unroll
    for (int i = 0; i < 4; ++i)
#pragma unroll
        for (int e = 0; e < 9; ++e) acc[i][e] = 0.0f;

#pragma unroll 1
    for (int ik = 0; ik < 5; ++ik) {
        const int k = ik - 2;
        float U[9];
#pragma unroll
        for (int e = 0; e < 9; ++e) U[e] = Ub[ik * 9 + e];

        // neighbor site along mu
        const int ns = s + ((((x + k + 16) & 15) - x) << sh);
        // own 4 channels: floats [jh*36 .. jh*36+35], 16B-aligned
        const float4* __restrict__ Wn4 =
            reinterpret_cast<const float4*>(W + (size_t)ns * 72 + jh * 36);
        float Wl[36];
#pragma unroll
        for (int q = 0; q < 9; ++q) {
            const float4 v = Wn4[q];
            Wl[q * 4 + 0] = v.x; Wl[q * 4 + 1] = v.y;
            Wl[q * 4 + 2] = v.z; Wl[q * 4 + 3] = v.w;
        }

#pragma unroll
        for (int t = 0; t < 4; ++t) {
            // sandwich M = U * W_{jh*4+t} * U^T  (channel t of Wl)
            float M[9];
#pragma unroll
            for (int a = 0; a < 3; ++a) {
                const float uw0 = fmaf(U[a * 3 + 0], Wl[t * 9 + 0],
                                  fmaf(U[a * 3 + 1], Wl[t * 9 + 3],
                                       U[a * 3 + 2] * Wl[t * 9 + 6]));
                const float uw1 = fmaf(U[a * 3 + 0], Wl[t * 9 + 1],
                                  fmaf(U[a * 3 + 1], Wl[t * 9 + 4],
                                       U[a * 3 + 2] * Wl[t * 9 + 7]));
                const float uw2 = fmaf(U[a * 3 + 0], Wl[t * 9 + 2],
                                  fmaf(U[a * 3 + 1], Wl[t * 9 + 5],
                                       U[a * 3 + 2] * Wl[t * 9 + 8]));
#pragma unroll
                for (int b2 = 0; b2 < 3; ++b2)
                    M[a * 3 + b2] = fmaf(uw0, U[b2 * 3 + 0],
                                    fmaf(uw1, U[b2 * 3 + 1],
                                         uw2 * U[b2 * 3 + 2]));
            }

            // omega for own-j and partner-j, own i-half: one float4 each,
            // conflict-free (8 lane classes span all 32 banks, 8-lane bcast)
            const float4 wo = *reinterpret_cast<const float4*>(
                                  omt + ik * 64 + jown8 + t * 8);
            const float4 wp = *reinterpret_cast<const float4*>(
                                  omt + ik * 64 + jpar8 + t * 8);
            const float wov[4] = {wo.x, wo.y, wo.z, wo.w};
            const float wpv[4] = {wp.x, wp.y, wp.z, wp.w};

            // mix own M and partner's M (exchanged via shfl_xor lane^4)
#pragma unroll
            for (int e = 0; e < 9; ++e) {
                const float mp = __shfl_xor(M[e], 4);
#pragma unroll
                for (int ii = 0; ii < 4; ++ii)
                    acc[ii][e] = fmaf(wov[ii], M[e],
                                 fmaf(wpv[ii], mp, acc[ii][e]));
            }
        }
    }

    // reduce the 4 mu-partials within each mu-quad
#pragma unroll
    for (int i = 0; i < 4; ++i)
#pragma unroll
        for (int e = 0; e < 9; ++e) {
            float v = acc[i][e];
            v += __shfl_xor(v, 1);
            v += __shfl_xor(v, 2);
            acc[i][e] = v;
        }

    // mu==0 lanes (2 per site) store their 36-float half-block (9 float4)
    if (mu == 0) {
        float4* __restrict__ o4 =
            reinterpret_cast<float4*>(out + (size_t)s * 72 + jh * 36);
#pragma unroll
        for (int q = 0; q < 9; ++q) {
            const int f = q * 4;
            o4[q] = make_float4(acc[(f + 0) / 9][(f + 0) % 9],
                                acc[(f + 1) / 9][(f + 1) % 9],
                                acc[(f + 2) / 9][(f + 2) % 9],
                                acc[(f + 3) / 9][(f + 3) % 9]);
        }
    }
}

extern "C" void kernel_launch(void* const* d_in, const int* in_sizes, int n_in,
                              void* d_out, int out_size, void* d_ws, size_t ws_size,
                              hipStream_t stream) {
    const float* W   = (const float*)d_in[0];
    const float* U   = (const float*)d_in[1];
    const float* om  = (const float*)d_in[2];
    float*       out = (float*)d_out;

    const int block = 256;
    const int grid  = (NSITES * 8) / block;   // 4096 blocks
    hipLaunchKernelGGL(lconv_kernel, dim3(grid), dim3(block), 0, stream,
                       W, U, om, out);
}